// Round 4
// baseline (304.613 us; speedup 1.0000x reference)
//
#include <hip/hip_runtime.h>
#include <hip/hip_bf16.h>
#include <cstdint>
#include <cstddef>

// RGCN layer, fused: out[n] = (sum_r h_r[n]@W[r] + x[n]@W0) / max(deg,1)
// Edges CSR'd by key = dst*8 + type (3-level scan over N*8 bins).
// k_fused: per block (64 nodes): for each relation r, gather bf16 x rows into
// swizzled LDS A-tile (double-buffered), MFMA vs Wb[r] (global, L2-resident),
// accumulate 64x128 out. No h intermediate (-228 MB HBM traffic vs round 3).

#define NDIM 128
#define NREL 8
#define KCAT 1152   // 9*128

typedef __attribute__((ext_vector_type(8))) short bf16x8;
typedef __attribute__((ext_vector_type(4))) float f32x4;
typedef unsigned int uint32;
typedef unsigned short ushort16;

__device__ __forceinline__ short f2bf(float f){
  __hip_bfloat16 h = __float2bfloat16(f);
  return *reinterpret_cast<short*>(&h);
}
__device__ __forceinline__ float bfl(uint32 v){ return __uint_as_float(v << 16); }
__device__ __forceinline__ float bfh(uint32 v){ return __uint_as_float(v & 0xFFFF0000u); }

// ---------- K0: zero int buffer ----------
__global__ void k_zero(int* p, int n){
  int i = blockIdx.x * 256 + threadIdx.x;
  if (i < n) p[i] = 0;
}

// ---------- K1: detect int64 vs int32 edge arrays ----------
__global__ void k_detect(const int* ei, int* flag){
  int v = ei[2 * threadIdx.x + 1];
  unsigned long long b = __ballot(v == 0);
  if (threadIdx.x == 0) flag[0] = (b == ~0ull) ? 1 : 0;
}

// ---------- K2: normalize edges: key = dst*8+type, histogram ----------
__global__ void k_norm2(const int* ei, const int* et, const int* __restrict__ flag,
                        int* sarr, int* karr, int* deg2, int E){
  int e = blockIdx.x * 256 + threadIdx.x;
  if (e >= E) return;
  int is64 = flag[0];
  int s, d, t;
  if (is64){ s = ei[2*e]; d = ei[2*(E + e)]; t = et[2*e]; }
  else     { s = ei[e];   d = ei[E + e];     t = et[e];   }
  int key = d * 8 + t;
  sarr[e] = s;
  karr[e] = key;
  atomicAdd(&deg2[key], 1);
}

// ---------- scan: generic per-block exclusive scan + block sums ----------
__global__ void k_scanA(const int* src, int* dst, int* bsum, int M){
  __shared__ int sm[256];
  int t = threadIdx.x, i = blockIdx.x * 256 + t;
  int v = (i < M) ? src[i] : 0;
  sm[t] = v; __syncthreads();
  #pragma unroll
  for (int off = 1; off < 256; off <<= 1){
    int xv = 0; if (t >= off) xv = sm[t - off];
    __syncthreads(); sm[t] += xv; __syncthreads();
  }
  if (i < M) dst[i] = sm[t] - v;
  if (t == 255) bsum[blockIdx.x] = sm[255];
}

__global__ void k_scanB(const int* bsum, int* boff, int nblk){
  __shared__ int sm[256];
  int t = threadIdx.x;
  int v = (t < nblk) ? bsum[t] : 0;
  sm[t] = v; __syncthreads();
  #pragma unroll
  for (int off = 1; off < 256; off <<= 1){
    int xv = 0; if (t >= off) xv = sm[t - off];
    __syncthreads(); sm[t] += xv; __syncthreads();
  }
  boff[t] = sm[t] - v;
}

__global__ void k_fixA(int* boff0, const int* boff1, int n){
  int i = blockIdx.x * 256 + threadIdx.x;
  if (i < n) boff0[i] += boff1[i >> 8];
}

__global__ void k_fixB(int* rs2, const int* boff0, int* cur2, int M, int E){
  int i = blockIdx.x * 256 + threadIdx.x;
  if (i < M){
    int v = rs2[i] + boff0[i >> 8];
    rs2[i] = v; cur2[i] = v;
  }
  if (i == 0) rs2[M] = E;
}

// ---------- K6: scatter srcs into (dst,type)-CSR order ----------
__global__ void k_scatter2(const int* sarr, const int* karr, int* cur2, int* esort, int E){
  int e = blockIdx.x * 256 + threadIdx.x;
  if (e >= E) return;
  int pos = atomicAdd(&cur2[karr[e]], 1);
  esort[pos] = sarr[e];
}

// ---------- K7: x f32 -> bf16 ----------
__global__ void k_xcast(const float* __restrict__ x, ushort16* __restrict__ xb, int n4){
  int i = blockIdx.x * 256 + threadIdx.x;
  if (i >= n4) return;
  float4 f = ((const float4*)x)[i];
  ushort4 o;
  o.x = (ushort16)f2bf(f.x); o.y = (ushort16)f2bf(f.y);
  o.z = (ushort16)f2bf(f.z); o.w = (ushort16)f2bf(f.w);
  ((ushort4*)xb)[i] = o;
}

// ---------- K8: W,W0 -> Wb[j][KCAT] bf16: Wb[j][r*128+kd] = W[r][kd][j] ----------
__global__ void k_wcast(const float* __restrict__ W, const float* __restrict__ W0,
                        short* __restrict__ Wb){
  int i = blockIdx.x * 256 + threadIdx.x;      // 128*1152
  if (i >= NDIM * KCAT) return;
  int j  = i / KCAT;
  int t  = i - j * KCAT;
  int r  = t >> 7;
  int kd = t & 127;
  float v = (r < NREL) ? W[(((size_t)r * NDIM + kd) << 7) + j] : W0[((size_t)kd << 7) + j];
  Wb[i] = f2bf(v);
}

// ---------- K9: fused gather + MFMA ----------
// 64 nodes/block, 4 waves (wave w gathers rows w*16..w*16+15).
// Per relation: gather next slice into LDS buf^1 while MFMA'ing buf with Wb[r].
// LDS A-tile [64][128] bf16, 16B-chunk XOR swizzle (chunk ^= row&7) both sides.
__global__ __launch_bounds__(256) void k_fused(
    const ushort16* __restrict__ xb,  // [N][128] bf16
    const int* __restrict__ rs2,      // [N*8+1] CSR by dst*8+type
    const int* __restrict__ esort,    // [E] src ids
    const short* __restrict__ wb,     // [128][1152] bf16
    float* __restrict__ out, int N)
{
  __shared__ short Abuf[2][64 * 128];    // 2 x 16 KB
  const int tid  = threadIdx.x;
  const int lane = tid & 63;
  const int wid  = tid >> 6;
  const int wr   = wid >> 1;
  const int wc   = wid & 1;
  const int lr   = lane & 15;
  const int lq   = lane >> 4;
  const int n0   = blockIdx.x * 64;
  const int nbase = n0 + wid * 16;

  f32x4 acc[2][4];
  #pragma unroll
  for (int m = 0; m < 2; ++m)
    #pragma unroll
    for (int p = 0; p < 4; ++p)
      acc[m][p] = (f32x4){0.f, 0.f, 0.f, 0.f};

  auto GATHER = [&](short* A, int r){
    // lanes 0..15 hold edge-range boundaries for the wave's 16 nodes
    int bi = 0, ee = 0;
    if (r < NREL){
      int nn = nbase + lr;
      if (nn < N){
        bi = rs2[nn * 8 + r];
        ee = rs2[nn * 8 + r + 1];
      }
    }
    #pragma unroll
    for (int i = 0; i < 16; ++i){
      int row = wid * 16 + i;
      int n = nbase + i;
      float sx = 0.f, sy = 0.f;
      if (r == NREL){
        if (n < N){
          uint32 v = *(const uint32*)(xb + (size_t)n * 128 + 2 * lane);
          sx = bfl(v); sy = bfh(v);
        }
      } else {
        int beg = __builtin_amdgcn_readlane(bi, i);
        int end = __builtin_amdgcn_readlane(ee, i);
        for (int e = beg; e < end; e += 4){
          int e1 = min(e + 1, end - 1);
          int e2 = min(e + 2, end - 1);
          int e3 = min(e + 3, end - 1);
          int s0 = esort[e],  s1 = esort[e1];
          int s2 = esort[e2], s3 = esort[e3];
          uint32 v0 = *(const uint32*)(xb + (size_t)s0 * 128 + 2 * lane);
          uint32 v1 = *(const uint32*)(xb + (size_t)s1 * 128 + 2 * lane);
          uint32 v2 = *(const uint32*)(xb + (size_t)s2 * 128 + 2 * lane);
          uint32 v3 = *(const uint32*)(xb + (size_t)s3 * 128 + 2 * lane);
          sx += bfl(v0); sy += bfh(v0);
          if (e + 1 < end){ sx += bfl(v1); sy += bfh(v1); }
          if (e + 2 < end){ sx += bfl(v2); sy += bfh(v2); }
          if (e + 3 < end){ sx += bfl(v3); sy += bfh(v3); }
        }
      }
      __hip_bfloat162 pk = __float22bfloat162_rn(make_float2(sx, sy));
      uint32 w = *reinterpret_cast<uint32*>(&pk);
      int c = lane >> 2;                       // 16B chunk 0..15
      int byte = row * 256 + ((c ^ (row & 7)) << 4) + (lane & 3) * 4;
      *(uint32*)((char*)A + byte) = w;
    }
  };

  auto MMA = [&](const short* A, int r){
    bf16x8 b[4][4];
    #pragma unroll
    for (int kk = 0; kk < 4; ++kk)
      #pragma unroll
      for (int p = 0; p < 4; ++p){
        int j = wc * 64 + p * 16 + lr;
        b[kk][p] = *(const bf16x8*)(wb + (size_t)j * KCAT + r * 128 + kk * 32 + lq * 8);
      }
    #pragma unroll
    for (int kk = 0; kk < 4; ++kk){
      bf16x8 a[2];
      #pragma unroll
      for (int m = 0; m < 2; ++m){
        int row = wr * 32 + m * 16 + lr;
        int c = kk * 4 + lq;
        a[m] = *(const bf16x8*)((const char*)A + row * 256 + ((c ^ (row & 7)) << 4));
      }
      #pragma unroll
      for (int m = 0; m < 2; ++m)
        #pragma unroll
        for (int p = 0; p < 4; ++p)
          acc[m][p] = __builtin_amdgcn_mfma_f32_16x16x32_bf16(a[m], b[kk][p], acc[m][p], 0, 0, 0);
    }
  };

  GATHER(Abuf[0], 0);
  __syncthreads();
  #pragma unroll 1
  for (int r = 0; r <= NREL; ++r){
    short* cur = Abuf[r & 1];
    short* nxt = Abuf[(r & 1) ^ 1];
    if (r < NREL) GATHER(nxt, r + 1);
    MMA(cur, r);
    __syncthreads();
  }

  // Epilogue: C/D layout col=lane&15, row=(lane>>4)*4+v; invdeg from rs2.
  #pragma unroll
  for (int m = 0; m < 2; ++m){
    int rbase = n0 + wr * 32 + m * 16 + lq * 4;
    #pragma unroll
    for (int v = 0; v < 4; ++v){
      int ro = rbase + v;
      if (ro < N){
        int dg = rs2[ro * 8 + 8] - rs2[ro * 8];
        float inv = 1.0f / (float)(dg > 0 ? dg : 1);
        #pragma unroll
        for (int p = 0; p < 4; ++p)
          out[(((size_t)ro) << 7) + wc * 64 + p * 16 + lr] = acc[m][p][v] * inv;
      }
    }
  }
}

extern "C" void kernel_launch(void* const* d_in, const int* in_sizes, int n_in,
                              void* d_out, int out_size, void* d_ws, size_t ws_size,
                              hipStream_t stream){
  const float* x  = (const float*)d_in[0];
  const int*   ei = (const int*)d_in[1];
  const int*   et = (const int*)d_in[2];
  const float* W  = (const float*)d_in[4];
  const float* W0 = (const float*)d_in[5];
  float* out = (float*)d_out;

  const int N = in_sizes[0] / NDIM;   // 50000
  const int E = in_sizes[2];          // 800000
  const int M = N * NREL;             // 400000 bins

  char* ws = (char*)d_ws;
  size_t off = 0;
  auto alloc = [&](size_t bytes)->size_t{
    size_t p = off; off = (off + bytes + 255) & ~(size_t)255; return p;
  };
  size_t o_flag = alloc(4);
  size_t o_s    = alloc((size_t)E * 4);
  size_t o_k    = alloc((size_t)E * 4);
  size_t o_deg2 = alloc((size_t)M * 4);
  size_t o_rs2  = alloc((size_t)(M + 1) * 4);
  size_t o_cur2 = alloc((size_t)M * 4);
  size_t o_bs0  = alloc(2048 * 4);
  size_t o_bo0  = alloc(2048 * 4);
  size_t o_bs1  = alloc(256 * 4);
  size_t o_bo1  = alloc(256 * 4);
  size_t o_es   = alloc((size_t)E * 4);
  size_t o_xb   = alloc((size_t)N * NDIM * 2);
  size_t o_wb   = alloc((size_t)NDIM * KCAT * 2);
  (void)ws_size;

  int* flag  = (int*)(ws + o_flag);
  int* sarr  = (int*)(ws + o_s);
  int* karr  = (int*)(ws + o_k);
  int* deg2  = (int*)(ws + o_deg2);
  int* rs2   = (int*)(ws + o_rs2);
  int* cur2  = (int*)(ws + o_cur2);
  int* bsum0 = (int*)(ws + o_bs0);
  int* boff0 = (int*)(ws + o_bo0);
  int* bsum1 = (int*)(ws + o_bs1);
  int* boff1 = (int*)(ws + o_bo1);
  int* esort = (int*)(ws + o_es);
  ushort16* xb = (ushort16*)(ws + o_xb);
  short* Wbs = (short*)(ws + o_wb);

  const int eblk  = (E + 255) / 256;       // 3125
  const int mblk  = (M + 255) / 256;       // 1563
  const int mblk1 = (mblk + 255) / 256;    // 7

  k_xcast<<<(N * NDIM / 4 + 255) / 256, 256, 0, stream>>>(x, xb, N * NDIM / 4);
  k_wcast<<<(NDIM * KCAT + 255) / 256, 256, 0, stream>>>(W, W0, Wbs);
  k_zero<<<mblk, 256, 0, stream>>>(deg2, M);
  k_detect<<<1, 64, 0, stream>>>(ei, flag);
  k_norm2<<<eblk, 256, 0, stream>>>(ei, et, flag, sarr, karr, deg2, E);
  k_scanA<<<mblk, 256, 0, stream>>>(deg2, rs2, bsum0, M);
  k_scanA<<<mblk1, 256, 0, stream>>>(bsum0, boff0, bsum1, mblk);
  k_scanB<<<1, 256, 0, stream>>>(bsum1, boff1, mblk1);
  k_fixA<<<mblk1, 256, 0, stream>>>(boff0, boff1, mblk);
  k_fixB<<<mblk, 256, 0, stream>>>(rs2, boff0, cur2, M, E);
  k_scatter2<<<eblk, 256, 0, stream>>>(sarr, karr, cur2, esort, E);
  k_fused<<<(N + 63) / 64, 256, 0, stream>>>(xb, rs2, esort, Wbs, out, N);
}

// Round 5
// 192.248 us; speedup vs baseline: 1.5845x; 1.5845x over previous
//
#include <hip/hip_runtime.h>
#include <hip/hip_bf16.h>
#include <cstdint>
#include <cstddef>

// RGCN layer: out = (x@W0 + sum_r h_r@W[r]) / max(deg,1)
// Round-3 split structure (proven) + bf16 gather:
//   xcast: x -> xb (bf16, 12.8 MB, cache-resident)
//   agg:   CSR-by-dst gather of xb rows -> h_cat[n][1152] bf16 (+ self slot)
//   gemm:  one GEMM [N,1152]@[1152,128] (m97 structure, swizzled LDS, gl_lds 16B)

#define NDIM 128
#define NREL 8
#define KCAT 1152   // 9*128

typedef __attribute__((ext_vector_type(8))) short bf16x8;
typedef __attribute__((ext_vector_type(4))) float f32x4;
typedef unsigned int uint32;

__device__ __forceinline__ short f2bf(float f){
  __hip_bfloat16 h = __float2bfloat16(f);
  return *reinterpret_cast<short*>(&h);
}
__device__ __forceinline__ float bfl(uint32 v){ return __uint_as_float(v << 16); }
__device__ __forceinline__ float bfh(uint32 v){ return __uint_as_float(v & 0xFFFF0000u); }

__device__ __forceinline__ void gload_lds16(const void* g, void* l){
  __builtin_amdgcn_global_load_lds(
      (const __attribute__((address_space(1))) unsigned int*)g,
      (__attribute__((address_space(3))) unsigned int*)l, 16, 0, 0);
}

// ---------- K0: zero int buffer ----------
__global__ void k_zero(int* p, int n){
  int i = blockIdx.x * 256 + threadIdx.x;
  if (i < n) p[i] = 0;
}

// ---------- K1: detect int64 vs int32 edge arrays ----------
__global__ void k_detect(const int* ei, int* flag){
  int v = ei[2 * threadIdx.x + 1];
  unsigned long long b = __ballot(v == 0);
  if (threadIdx.x == 0) flag[0] = (b == ~0ull) ? 1 : 0;
}

// ---------- K2: normalize edges + degree histogram ----------
__global__ void k_norm(const int* ei, const int* et, const int* __restrict__ flag,
                       int* st, int* darr, int* deg, int E){
  int e = blockIdx.x * 256 + threadIdx.x;
  if (e >= E) return;
  int is64 = flag[0];
  int s, d, t;
  if (is64){ s = ei[2*e]; d = ei[2*(E + e)]; t = et[2*e]; }
  else     { s = ei[e];   d = ei[E + e];     t = et[e];   }
  st[e]   = s | (t << 20);
  darr[e] = d;
  atomicAdd(&deg[d], 1);
}

// ---------- K3/K4/K5: exclusive scan ----------
__global__ void k_scanA(const int* deg, int* rs, int* bsum, int N){
  __shared__ int sm[256];
  int t = threadIdx.x, i = blockIdx.x * 256 + t;
  int v = (i < N) ? deg[i] : 0;
  sm[t] = v; __syncthreads();
  #pragma unroll
  for (int off = 1; off < 256; off <<= 1){
    int xv = 0; if (t >= off) xv = sm[t - off];
    __syncthreads(); sm[t] += xv; __syncthreads();
  }
  if (i < N) rs[i] = sm[t] - v;
  if (t == 255) bsum[blockIdx.x] = sm[255];
}

__global__ void k_scanB(const int* bsum, int* boff, int nblk){
  __shared__ int sm[256];
  int t = threadIdx.x;
  int v = (t < nblk) ? bsum[t] : 0;
  sm[t] = v; __syncthreads();
  #pragma unroll
  for (int off = 1; off < 256; off <<= 1){
    int xv = 0; if (t >= off) xv = sm[t - off];
    __syncthreads(); sm[t] += xv; __syncthreads();
  }
  boff[t] = sm[t] - v;
}

__global__ void k_scanC(int* rs, int* cursor, const int* boff, int N, int E){
  int i = blockIdx.x * 256 + threadIdx.x;
  if (i < N){
    int v = rs[i] + boff[blockIdx.x];
    rs[i] = v; cursor[i] = v;
  }
  if (i == 0) rs[N] = E;
}

// ---------- K6: scatter edges into CSR buckets ----------
__global__ void k_scatter(const int* st, const int* darr, int* cursor, int* esort, int E){
  int e = blockIdx.x * 256 + threadIdx.x;
  if (e >= E) return;
  int pos = atomicAdd(&cursor[darr[e]], 1);
  esort[pos] = st[e];
}

// ---------- K7a: x f32 -> bf16 ----------
__global__ void k_xcast(const float* __restrict__ x, uint32* __restrict__ xb, int n4){
  int i = blockIdx.x * 256 + threadIdx.x;
  if (i >= n4) return;
  float4 f = ((const float4*)x)[i];
  uint32 lo = ((uint32)(unsigned short)f2bf(f.x)) | (((uint32)(unsigned short)f2bf(f.y)) << 16);
  uint32 hi = ((uint32)(unsigned short)f2bf(f.z)) | (((uint32)(unsigned short)f2bf(f.w)) << 16);
  ((uint2*)xb)[i] = make_uint2(lo, hi);
}

// ---------- K7b: aggregation (bf16 gather) -> h_cat[n][1152] bf16, invdeg ----------
// 1 wave per node; lane owns cols {2l,2l+1} via one uint32; 4-wide edge unroll.
__global__ __launch_bounds__(256) void k_agg(const uint32* __restrict__ xb,
                                             const int* __restrict__ rs,
                                             const int* __restrict__ esort,
                                             uint32* __restrict__ hcat,
                                             float* __restrict__ invdeg, int N){
  int wave = threadIdx.x >> 6;
  int lane = threadIdx.x & 63;
  int n = blockIdx.x * 4 + wave;
  if (n >= N) return;
  int beg = rs[n], end = rs[n + 1];
  float2 acc[NREL];
  #pragma unroll
  for (int r = 0; r < NREL; ++r){ acc[r].x = 0.f; acc[r].y = 0.f; }

  int i = beg;
  for (; i + 3 < end; i += 4){
    int p0 = esort[i], p1 = esort[i+1], p2 = esort[i+2], p3 = esort[i+3];
    uint32 v0 = xb[(size_t)(p0 & 0xFFFFF) * 64 + lane];
    uint32 v1 = xb[(size_t)(p1 & 0xFFFFF) * 64 + lane];
    uint32 v2 = xb[(size_t)(p2 & 0xFFFFF) * 64 + lane];
    uint32 v3 = xb[(size_t)(p3 & 0xFFFFF) * 64 + lane];
    switch (p0 >> 20){
      case 0: acc[0].x+=bfl(v0); acc[0].y+=bfh(v0); break; case 1: acc[1].x+=bfl(v0); acc[1].y+=bfh(v0); break;
      case 2: acc[2].x+=bfl(v0); acc[2].y+=bfh(v0); break; case 3: acc[3].x+=bfl(v0); acc[3].y+=bfh(v0); break;
      case 4: acc[4].x+=bfl(v0); acc[4].y+=bfh(v0); break; case 5: acc[5].x+=bfl(v0); acc[5].y+=bfh(v0); break;
      case 6: acc[6].x+=bfl(v0); acc[6].y+=bfh(v0); break; case 7: acc[7].x+=bfl(v0); acc[7].y+=bfh(v0); break;
    }
    switch (p1 >> 20){
      case 0: acc[0].x+=bfl(v1); acc[0].y+=bfh(v1); break; case 1: acc[1].x+=bfl(v1); acc[1].y+=bfh(v1); break;
      case 2: acc[2].x+=bfl(v1); acc[2].y+=bfh(v1); break; case 3: acc[3].x+=bfl(v1); acc[3].y+=bfh(v1); break;
      case 4: acc[4].x+=bfl(v1); acc[4].y+=bfh(v1); break; case 5: acc[5].x+=bfl(v1); acc[5].y+=bfh(v1); break;
      case 6: acc[6].x+=bfl(v1); acc[6].y+=bfh(v1); break; case 7: acc[7].x+=bfl(v1); acc[7].y+=bfh(v1); break;
    }
    switch (p2 >> 20){
      case 0: acc[0].x+=bfl(v2); acc[0].y+=bfh(v2); break; case 1: acc[1].x+=bfl(v2); acc[1].y+=bfh(v2); break;
      case 2: acc[2].x+=bfl(v2); acc[2].y+=bfh(v2); break; case 3: acc[3].x+=bfl(v2); acc[3].y+=bfh(v2); break;
      case 4: acc[4].x+=bfl(v2); acc[4].y+=bfh(v2); break; case 5: acc[5].x+=bfl(v2); acc[5].y+=bfh(v2); break;
      case 6: acc[6].x+=bfl(v2); acc[6].y+=bfh(v2); break; case 7: acc[7].x+=bfl(v2); acc[7].y+=bfh(v2); break;
    }
    switch (p3 >> 20){
      case 0: acc[0].x+=bfl(v3); acc[0].y+=bfh(v3); break; case 1: acc[1].x+=bfl(v3); acc[1].y+=bfh(v3); break;
      case 2: acc[2].x+=bfl(v3); acc[2].y+=bfh(v3); break; case 3: acc[3].x+=bfl(v3); acc[3].y+=bfh(v3); break;
      case 4: acc[4].x+=bfl(v3); acc[4].y+=bfh(v3); break; case 5: acc[5].x+=bfl(v3); acc[5].y+=bfh(v3); break;
      case 6: acc[6].x+=bfl(v3); acc[6].y+=bfh(v3); break; case 7: acc[7].x+=bfl(v3); acc[7].y+=bfh(v3); break;
    }
  }
  for (; i < end; ++i){
    int p = esort[i];
    uint32 v = xb[(size_t)(p & 0xFFFFF) * 64 + lane];
    switch (p >> 20){
      case 0: acc[0].x+=bfl(v); acc[0].y+=bfh(v); break; case 1: acc[1].x+=bfl(v); acc[1].y+=bfh(v); break;
      case 2: acc[2].x+=bfl(v); acc[2].y+=bfh(v); break; case 3: acc[3].x+=bfl(v); acc[3].y+=bfh(v); break;
      case 4: acc[4].x+=bfl(v); acc[4].y+=bfh(v); break; case 5: acc[5].x+=bfl(v); acc[5].y+=bfh(v); break;
      case 6: acc[6].x+=bfl(v); acc[6].y+=bfh(v); break; case 7: acc[7].x+=bfl(v); acc[7].y+=bfh(v); break;
    }
  }

  size_t base = (size_t)n * (KCAT / 2);
  #pragma unroll
  for (int r = 0; r < NREL; ++r){
    __hip_bfloat162 pk = __float22bfloat162_rn(make_float2(acc[r].x, acc[r].y));
    hcat[base + r * 64 + lane] = *reinterpret_cast<uint32*>(&pk);
  }
  hcat[base + 512 + lane] = xb[(size_t)n * 64 + lane];   // self slot, bit-copy
  if (lane == 0){
    int d = end - beg;
    invdeg[n] = 1.0f / (float)(d > 0 ? d : 1);
  }
}

// ---------- K8a: W,W0 -> Wb[j][KCAT] bf16: Wb[j][r*128+kd] = W[r][kd][j] ----------
__global__ void k_wcast(const float* __restrict__ W, const float* __restrict__ W0,
                        short* __restrict__ Wb){
  int i = blockIdx.x * 256 + threadIdx.x;      // 128*1152
  if (i >= NDIM * KCAT) return;
  int j  = i / KCAT;
  int t  = i - j * KCAT;
  int r  = t >> 7;
  int kd = t & 127;
  float v = (r < NREL) ? W[(((size_t)r * NDIM + kd) << 7) + j] : W0[((size_t)kd << 7) + j];
  Wb[i] = f2bf(v);
}

// ---------- K8b: GEMM out[n][j] = (A[n][:] . Wb[j][:]) * invdeg[n] ----------
// BM=64, BN=128, BK=64; 4 waves, wave tile 32x64 (2x4 frags of 16x16x32 bf16).
// m97 structure: gl_lds(16B) double-buffer, XOR-swizzled LDS.
__global__ __launch_bounds__(256) void k_gemm2(
    const short* __restrict__ acat,   // [Npad][1152] bf16
    const short* __restrict__ wb,     // [128][1152]  bf16
    const float* __restrict__ invdeg,
    float* __restrict__ out, int N)
{
  __shared__ char smem[49152];
  char* As0 = smem;
  char* As1 = smem + 8192;
  char* Bs0 = smem + 16384;
  char* Bs1 = smem + 32768;

  const int tid  = threadIdx.x;
  const int lane = tid & 63;
  const int wid  = tid >> 6;
  const int wr   = wid >> 1;
  const int wc   = wid & 1;
  const int n0   = blockIdx.x * 64;
  const int lr   = lane & 15;
  const int lq   = lane >> 4;

  f32x4 acc[2][4];
  #pragma unroll
  for (int m = 0; m < 2; ++m)
    #pragma unroll
    for (int p = 0; p < 4; ++p)
      acc[m][p] = (f32x4){0.f, 0.f, 0.f, 0.f};

  const int srow = tid >> 3;
  const int scs  = tid & 7;

  auto STAGE = [&](char* Ab, char* Bb, int ks){
    const short* ab = acat + (size_t)n0 * KCAT + ks * 64;
    #pragma unroll
    for (int q = 0; q < 2; ++q){
      int row = q * 32 + srow;
      const short* src = ab + (size_t)row * KCAT + ((scs ^ (row & 7)) << 3);
      gload_lds16(src, Ab + q * 4096 + (wid << 10));
    }
    const short* bb = wb + ks * 64;
    #pragma unroll
    for (int q = 0; q < 4; ++q){
      int j = q * 32 + srow;
      const short* src = bb + (size_t)j * KCAT + ((scs ^ (j & 7)) << 3);
      gload_lds16(src, Bb + q * 4096 + (wid << 10));
    }
  };

  auto COMPUTE = [&](const char* Ab, const char* Bb){
    bf16x8 a[2][2], b[2][4];
    #pragma unroll
    for (int kk = 0; kk < 2; ++kk){
      #pragma unroll
      for (int m = 0; m < 2; ++m){
        int row = wr * 32 + m * 16 + lr;
        int c   = kk * 4 + lq;
        a[kk][m] = *(const bf16x8*)(Ab + row * 128 + ((c ^ (row & 7)) << 4));
      }
      #pragma unroll
      for (int p = 0; p < 4; ++p){
        int j = wc * 64 + p * 16 + lr;
        int c = kk * 4 + lq;
        b[kk][p] = *(const bf16x8*)(Bb + j * 128 + ((c ^ (j & 7)) << 4));
      }
    }
    #pragma unroll
    for (int kk = 0; kk < 2; ++kk)
      #pragma unroll
      for (int m = 0; m < 2; ++m)
        #pragma unroll
        for (int p = 0; p < 4; ++p)
          acc[m][p] = __builtin_amdgcn_mfma_f32_16x16x32_bf16(a[kk][m], b[kk][p], acc[m][p], 0, 0, 0);
  };

  STAGE(As0, Bs0, 0);
  __syncthreads();
  for (int ks = 0; ks < 18; ks += 2){
    STAGE(As1, Bs1, ks + 1);
    COMPUTE(As0, Bs0);
    __syncthreads();
    if (ks + 2 < 18) STAGE(As0, Bs0, ks + 2);
    COMPUTE(As1, Bs1);
    __syncthreads();
  }

  #pragma unroll
  for (int m = 0; m < 2; ++m){
    int rbase = n0 + wr * 32 + m * 16 + lq * 4;
    #pragma unroll
    for (int v = 0; v < 4; ++v){
      int ro = rbase + v;
      if (ro < N){
        float inv = invdeg[ro];
        #pragma unroll
        for (int p = 0; p < 4; ++p)
          out[(((size_t)ro) << 7) + wc * 64 + p * 16 + lr] = acc[m][p][v] * inv;
      }
    }
  }
}

extern "C" void kernel_launch(void* const* d_in, const int* in_sizes, int n_in,
                              void* d_out, int out_size, void* d_ws, size_t ws_size,
                              hipStream_t stream){
  const float* x  = (const float*)d_in[0];
  const int*   ei = (const int*)d_in[1];
  const int*   et = (const int*)d_in[2];
  const float* W  = (const float*)d_in[4];
  const float* W0 = (const float*)d_in[5];
  float* out = (float*)d_out;

  const int N = in_sizes[0] / NDIM;   // 50000
  const int E = in_sizes[2];          // 800000
  const int Npad = N + 64;

  char* ws = (char*)d_ws;
  size_t off = 0;
  auto alloc = [&](size_t bytes)->size_t{
    size_t p = off; off = (off + bytes + 255) & ~(size_t)255; return p;
  };
  size_t o_flag = alloc(4);
  size_t o_st   = alloc((size_t)E * 4);
  size_t o_d    = alloc((size_t)E * 4);
  size_t o_deg  = alloc((size_t)N * 4);
  size_t o_rs   = alloc((size_t)(N + 1) * 4);
  size_t o_cur  = alloc((size_t)N * 4);
  size_t o_bs   = alloc(256 * 4);
  size_t o_bo   = alloc(256 * 4);
  size_t o_es   = alloc((size_t)E * 4);
  size_t o_h    = alloc((size_t)Npad * KCAT * 2);
  size_t o_inv  = alloc((size_t)N * 4);
  size_t o_wb   = alloc((size_t)NDIM * KCAT * 2);
  size_t o_xb   = alloc((size_t)N * NDIM * 2);
  (void)ws_size;

  int*  flag   = (int*)(ws + o_flag);
  int*  st     = (int*)(ws + o_st);
  int*  darr   = (int*)(ws + o_d);
  int*  deg    = (int*)(ws + o_deg);
  int*  rs     = (int*)(ws + o_rs);
  int*  cursor = (int*)(ws + o_cur);
  int*  bsum   = (int*)(ws + o_bs);
  int*  boff   = (int*)(ws + o_bo);
  int*  esort  = (int*)(ws + o_es);
  uint32* hcat = (uint32*)(ws + o_h);
  short* acat  = (short*)(ws + o_h);
  float* invdeg = (float*)(ws + o_inv);
  short* Wbs   = (short*)(ws + o_wb);
  uint32* xb   = (uint32*)(ws + o_xb);

  const int nblk = (N + 255) / 256;
  const int eblk = (E + 255) / 256;

  k_xcast<<<(N * NDIM / 4 + 255) / 256, 256, 0, stream>>>(x, xb, N * NDIM / 4);
  k_wcast<<<(NDIM * KCAT + 255) / 256, 256, 0, stream>>>(W, W0, Wbs);
  k_zero<<<nblk, 256, 0, stream>>>(deg, N);
  k_detect<<<1, 64, 0, stream>>>(ei, flag);
  k_norm<<<eblk, 256, 0, stream>>>(ei, et, flag, st, darr, deg, E);
  k_scanA<<<nblk, 256, 0, stream>>>(deg, rs, bsum, N);
  k_scanB<<<1, 256, 0, stream>>>(bsum, boff, nblk);
  k_scanC<<<nblk, 256, 0, stream>>>(rs, cursor, boff, N, E);
  k_scatter<<<eblk, 256, 0, stream>>>(st, darr, cursor, esort, E);
  k_agg<<<(N + 3) / 4, 256, 0, stream>>>(xb, rs, esort, hcat, invdeg, N);
  k_gemm2<<<(N + 63) / 64, 256, 0, stream>>>(acat, Wbs, invdeg, out, N);
}